// Round 1
// baseline (3466.135 us; speedup 1.0000x reference)
//
#include <hip/hip_runtime.h>

#define N_TOTAL 1024000
#define N_EDGES 16384000
#define SLOPE 0.01f

__device__ __forceinline__ float lrelu(float v){ return v > 0.0f ? v : SLOPE*v; }

// P[i] = x[i] @ w0a ; Q[i] = P[i] + b0a
__global__ void __launch_bounds__(256) k_init(const float* __restrict__ x,
                       const float* __restrict__ w,   // 16x8
                       const float* __restrict__ b,   // 8
                       float* __restrict__ P, float* __restrict__ Q){
  int i = blockIdx.x*256 + threadIdx.x;
  if (i >= N_TOTAL) return;
  const float4* xr = (const float4*)(x + (size_t)i*16);
  float4 a0 = xr[0], a1 = xr[1], a2 = xr[2], a3 = xr[3];
  float xi[16] = {a0.x,a0.y,a0.z,a0.w, a1.x,a1.y,a1.z,a1.w,
                  a2.x,a2.y,a2.z,a2.w, a3.x,a3.y,a3.z,a3.w};
  float p[8];
  #pragma unroll
  for (int j=0;j<8;j++){
    float s = 0.f;
    #pragma unroll
    for (int k=0;k<16;k++) s += xi[k]*w[k*8+j];
    p[j] = s;
  }
  float4* Pr = (float4*)(P + (size_t)i*8);
  Pr[0] = make_float4(p[0],p[1],p[2],p[3]);
  Pr[1] = make_float4(p[4],p[5],p[6],p[7]);
  float4* Qr = (float4*)(Q + (size_t)i*8);
  Qr[0] = make_float4(p[0]+b[0],p[1]+b[1],p[2]+b[2],p[3]+b[3]);
  Qr[1] = make_float4(p[4]+b[4],p[5]+b[5],p[6]+b[6],p[7]+b[7]);
}

// For each edge: Q[dst] += P[src]; 8 lanes per edge (feature j = lane&7)
__global__ void __launch_bounds__(256) k_scatter(const int* __restrict__ src,
                                                 const int* __restrict__ dst,
                                                 const float* __restrict__ P,
                                                 float* __restrict__ Q){
  int t = blockIdx.x*256 + threadIdx.x;   // < 131,072,000 fits in int
  int e = t >> 3;
  int j = t & 7;
  int s = src[e];
  int d = dst[e];
  float v = P[(size_t)s*8 + j];
  atomicAdd(Q + (size_t)d*8 + j, v);
}

// Q -> finish prev conv MLP (wb,bb) -> inter-layer leaky -> next first linear (wa,ba)
// writes P and re-initializes Q = P + ba (in place on Q, per-row so no hazard)
__global__ void __launch_bounds__(256) k_mid(float* __restrict__ P, float* Q,
                      const float* __restrict__ wb, const float* __restrict__ bb,
                      const float* __restrict__ wa, const float* __restrict__ ba){
  int i = blockIdx.x*256 + threadIdx.x;
  if (i >= N_TOTAL) return;
  float4* Qr = (float4*)(Q + (size_t)i*8);
  float4 q0 = Qr[0], q1 = Qr[1];
  float g[8] = {lrelu(q0.x),lrelu(q0.y),lrelu(q0.z),lrelu(q0.w),
                lrelu(q1.x),lrelu(q1.y),lrelu(q1.z),lrelu(q1.w)};
  float h[8];
  #pragma unroll
  for (int j=0;j<8;j++){
    float s = bb[j];
    #pragma unroll
    for (int k=0;k<8;k++) s += g[k]*wb[k*8+j];
    h[j] = lrelu(s);     // conv output + inter-layer leaky (always applies for mid)
  }
  float p[8];
  #pragma unroll
  for (int j=0;j<8;j++){
    float s = 0.f;
    #pragma unroll
    for (int k=0;k<8;k++) s += h[k]*wa[k*8+j];
    p[j] = s;
  }
  float4* Pr = (float4*)(P + (size_t)i*8);
  Pr[0] = make_float4(p[0],p[1],p[2],p[3]);
  Pr[1] = make_float4(p[4],p[5],p[6],p[7]);
  Qr[0] = make_float4(p[0]+ba[0],p[1]+ba[1],p[2]+ba[2],p[3]+ba[3]);
  Qr[1] = make_float4(p[4]+ba[4],p[5]+ba[5],p[6]+ba[6],p[7]+ba[7]);
}

// Final conv MLP (w3b,b3b, NO inter-layer act) + fc1 + leaky + fc2 + log_softmax.
// One block per batch element.
__global__ void __launch_bounds__(256) k_readout(const float* __restrict__ Q,
                          const float* __restrict__ wb, const float* __restrict__ bb,
                          const float* __restrict__ fc1w, const float* __restrict__ fc1b,
                          const float* __restrict__ fc2w, const float* __restrict__ fc2b,
                          float* __restrict__ out){
  int bi = blockIdx.x;
  int tid = threadIdx.x;
  float acc0 = 0.f, acc1 = 0.f;
  for (int n = tid; n < 2000; n += 256){
    size_t i = (size_t)bi*2000 + n;
    const float4* qr = (const float4*)(Q + i*8);
    float4 q0 = qr[0], q1 = qr[1];
    float g[8] = {lrelu(q0.x),lrelu(q0.y),lrelu(q0.z),lrelu(q0.w),
                  lrelu(q1.x),lrelu(q1.y),lrelu(q1.z),lrelu(q1.w)};
    float s = fc1b[0];
    #pragma unroll
    for (int j=0;j<8;j++){
      float h = bb[j];
      #pragma unroll
      for (int k=0;k<8;k++) h += g[k]*wb[k*8+j];
      s += lrelu(h)*fc1w[j];   // h4 has no post-conv act; readout applies leaky(h4)
    }
    float t = lrelu(s);
    acc0 += t*fc2w[n*2+0];
    acc1 += t*fc2w[n*2+1];
  }
  #pragma unroll
  for (int off = 32; off > 0; off >>= 1){
    acc0 += __shfl_down(acc0, off);
    acc1 += __shfl_down(acc1, off);
  }
  __shared__ float s0[4], s1[4];
  int w = tid >> 6;
  if ((tid & 63) == 0){ s0[w] = acc0; s1[w] = acc1; }
  __syncthreads();
  if (tid == 0){
    float z0 = s0[0]+s0[1]+s0[2]+s0[3] + fc2b[0];
    float z1 = s1[0]+s1[1]+s1[2]+s1[3] + fc2b[1];
    float m = fmaxf(z0, z1);
    float lse = m + logf(expf(z0-m) + expf(z1-m));
    out[bi*2+0] = z0 - lse;
    out[bi*2+1] = z1 - lse;
  }
}

extern "C" void kernel_launch(void* const* d_in, const int* in_sizes, int n_in,
                              void* d_out, int out_size, void* d_ws, size_t ws_size,
                              hipStream_t stream){
  const float* x   = (const float*)d_in[0];
  const int*   ei  = (const int*)d_in[1];
  const int*   src = ei;
  const int*   dst = ei + N_EDGES;
  const float* w0a=(const float*)d_in[3],  *b0a=(const float*)d_in[4];
  const float* w0b=(const float*)d_in[5],  *b0b=(const float*)d_in[6];
  const float* w1a=(const float*)d_in[7],  *b1a=(const float*)d_in[8];
  const float* w1b=(const float*)d_in[9],  *b1b=(const float*)d_in[10];
  const float* w2a=(const float*)d_in[11], *b2a=(const float*)d_in[12];
  const float* w2b=(const float*)d_in[13], *b2b=(const float*)d_in[14];
  const float* w3a=(const float*)d_in[15], *b3a=(const float*)d_in[16];
  const float* w3b=(const float*)d_in[17], *b3b=(const float*)d_in[18];
  const float* fc1w=(const float*)d_in[19],*fc1b=(const float*)d_in[20];
  const float* fc2w=(const float*)d_in[21],*fc2b=(const float*)d_in[22];
  float* out = (float*)d_out;

  float* P = (float*)d_ws;                      // N_TOTAL*8 floats = 32.77 MB
  float* Q = P + (size_t)N_TOTAL*8;             // N_TOTAL*8 floats = 32.77 MB

  const int nb_nodes = (N_TOTAL + 255)/256;     // 4000
  const int nb_edges = (N_EDGES*8)/256;         // 512000

  k_init<<<nb_nodes,256,0,stream>>>(x, w0a, b0a, P, Q);
  k_scatter<<<nb_edges,256,0,stream>>>(src,dst,P,Q);
  k_mid<<<nb_nodes,256,0,stream>>>(P,Q,w0b,b0b,w1a,b1a);
  k_scatter<<<nb_edges,256,0,stream>>>(src,dst,P,Q);
  k_mid<<<nb_nodes,256,0,stream>>>(P,Q,w1b,b1b,w2a,b2a);
  k_scatter<<<nb_edges,256,0,stream>>>(src,dst,P,Q);
  k_mid<<<nb_nodes,256,0,stream>>>(P,Q,w2b,b2b,w3a,b3a);
  k_scatter<<<nb_edges,256,0,stream>>>(src,dst,P,Q);
  k_readout<<<512,256,0,stream>>>(Q,w3b,b3b,fc1w,fc1b,fc2w,fc2b,out);
}

// Round 2
// 2990.754 us; speedup vs baseline: 1.1590x; 1.1590x over previous
//
#include <hip/hip_runtime.h>

#define N_TOTAL 1024000
#define N_EDGES 16384000
#define SLOPE 0.01f

__device__ __forceinline__ float lrelu(float v){ return v > 0.0f ? v : SLOPE*v; }

// ---------------- node kernels ----------------

// P[i] = x[i] @ w0a   (bias added later by aggregator)
__global__ void __launch_bounds__(256) k_init(const float* __restrict__ x,
                       const float* __restrict__ w,   // 16x8
                       float* __restrict__ P){
  int i = blockIdx.x*256 + threadIdx.x;
  if (i >= N_TOTAL) return;
  const float4* xr = (const float4*)(x + (size_t)i*16);
  float4 a0 = xr[0], a1 = xr[1], a2 = xr[2], a3 = xr[3];
  float xi[16] = {a0.x,a0.y,a0.z,a0.w, a1.x,a1.y,a1.z,a1.w,
                  a2.x,a2.y,a2.z,a2.w, a3.x,a3.y,a3.z,a3.w};
  float p[8];
  #pragma unroll
  for (int j=0;j<8;j++){
    float s = 0.f;
    #pragma unroll
    for (int k=0;k<16;k++) s += xi[k]*w[k*8+j];
    p[j] = s;
  }
  float4* Pr = (float4*)(P + (size_t)i*8);
  Pr[0] = make_float4(p[0],p[1],p[2],p[3]);
  Pr[1] = make_float4(p[4],p[5],p[6],p[7]);
}

// Q -> lrelu -> @wb+bb -> lrelu -> @wa -> P   (bias of next layer added by aggregator)
__global__ void __launch_bounds__(256) k_mid(float* __restrict__ P, const float* __restrict__ Q,
                      const float* __restrict__ wb, const float* __restrict__ bb,
                      const float* __restrict__ wa){
  int i = blockIdx.x*256 + threadIdx.x;
  if (i >= N_TOTAL) return;
  const float4* Qr = (const float4*)(Q + (size_t)i*8);
  float4 q0 = Qr[0], q1 = Qr[1];
  float g[8] = {lrelu(q0.x),lrelu(q0.y),lrelu(q0.z),lrelu(q0.w),
                lrelu(q1.x),lrelu(q1.y),lrelu(q1.z),lrelu(q1.w)};
  float h[8];
  #pragma unroll
  for (int j=0;j<8;j++){
    float s = bb[j];
    #pragma unroll
    for (int k=0;k<8;k++) s += g[k]*wb[k*8+j];
    h[j] = lrelu(s);
  }
  float p[8];
  #pragma unroll
  for (int j=0;j<8;j++){
    float s = 0.f;
    #pragma unroll
    for (int k=0;k<8;k++) s += h[k]*wa[k*8+j];
    p[j] = s;
  }
  float4* Pr = (float4*)(P + (size_t)i*8);
  Pr[0] = make_float4(p[0],p[1],p[2],p[3]);
  Pr[1] = make_float4(p[4],p[5],p[6],p[7]);
}

// ---------------- CSR build ----------------

__global__ void __launch_bounds__(256) k_hist(const int* __restrict__ dst, int* __restrict__ deg){
  int t = blockIdx.x*256 + threadIdx.x;
  if (t < N_EDGES) atomicAdd(&deg[dst[t]], 1);
}

// block sums of deg, 1024 elems per block
__global__ void __launch_bounds__(256) k_scan1(const int* __restrict__ deg, int* __restrict__ partial){
  __shared__ int sums[256];
  int tid = threadIdx.x;
  int base = blockIdx.x*1024 + tid*4;
  int s = deg[base] + deg[base+1] + deg[base+2] + deg[base+3];
  sums[tid] = s; __syncthreads();
  for (int off=1; off<256; off<<=1){
    int t = (tid>=off) ? sums[tid-off] : 0; __syncthreads();
    sums[tid] += t; __syncthreads();
  }
  if (tid == 255) partial[blockIdx.x] = sums[255];
}

// exclusive scan of 1000 partials, single block
__global__ void __launch_bounds__(256) k_scan2(int* __restrict__ partial, int n){
  __shared__ int sums[256];
  int tid = threadIdx.x;
  int v[4]; int s = 0;
  #pragma unroll
  for (int k=0;k<4;k++){ int idx = tid*4+k; v[k] = (idx<n) ? partial[idx] : 0; s += v[k]; }
  sums[tid] = s; __syncthreads();
  for (int off=1; off<256; off<<=1){
    int t = (tid>=off) ? sums[tid-off] : 0; __syncthreads();
    sums[tid] += t; __syncthreads();
  }
  int run = (tid>0) ? sums[tid-1] : 0;
  #pragma unroll
  for (int k=0;k<4;k++){ int idx = tid*4+k; if (idx<n) partial[idx] = run; run += v[k]; }
}

// full exclusive scan: row_ptr[i], and pos[i]=row_ptr[i] (pos aliases deg)
__global__ void __launch_bounds__(256) k_scan3(int* __restrict__ deg, const int* __restrict__ partial,
                                               int* __restrict__ row_ptr, int* __restrict__ pos){
  __shared__ int sums[256];
  int tid = threadIdx.x;
  int base = blockIdx.x*1024 + tid*4;
  int v[4];
  #pragma unroll
  for (int k=0;k<4;k++) v[k] = deg[base+k];
  int s = v[0]+v[1]+v[2]+v[3];
  sums[tid] = s; __syncthreads();
  for (int off=1; off<256; off<<=1){
    int t = (tid>=off) ? sums[tid-off] : 0; __syncthreads();
    sums[tid] += t; __syncthreads();
  }
  int run = partial[blockIdx.x] + ((tid>0) ? sums[tid-1] : 0);
  #pragma unroll
  for (int k=0;k<4;k++){ row_ptr[base+k] = run; pos[base+k] = run; run += v[k]; }
  if (blockIdx.x == 0 && tid == 0) row_ptr[N_TOTAL] = N_EDGES;
}

__global__ void __launch_bounds__(256) k_fill(const int* __restrict__ src, const int* __restrict__ dst,
                                              int* __restrict__ pos, int* __restrict__ csr){
  int t = blockIdx.x*256 + threadIdx.x;
  if (t >= N_EDGES) return;
  int d = dst[t];
  int p = atomicAdd(&pos[d], 1);
  csr[p] = src[t];
}

// ---------------- aggregation (no atomics) ----------------
// Q[i][j] = P[i][j] + b[j] + sum_{s in N(i)} P[s][j]; 8 lanes per node
__global__ void __launch_bounds__(256) k_agg(const float* __restrict__ P,
                                             const int* __restrict__ row_ptr,
                                             const int* __restrict__ csr,
                                             const float* __restrict__ b,
                                             float* __restrict__ Q){
  int t = blockIdx.x*256 + threadIdx.x;
  int node = t >> 3;
  int j = t & 7;
  if (node >= N_TOTAL) return;
  int beg = row_ptr[node], end = row_ptr[node+1];
  float acc = P[(size_t)node*8 + j] + b[j];
  int e = beg;
  for (; e+1 < end; e += 2){
    int s0 = csr[e], s1 = csr[e+1];
    float v0 = P[(size_t)s0*8 + j];
    float v1 = P[(size_t)s1*8 + j];
    acc += v0; acc += v1;
  }
  if (e < end) acc += P[(size_t)csr[e]*8 + j];
  Q[(size_t)node*8 + j] = acc;
}

// ---------------- fallback (atomic path) ----------------
__global__ void __launch_bounds__(256) k_qinit(const float* __restrict__ P, const float* __restrict__ b,
                                               float* __restrict__ Q){
  int t = blockIdx.x*256 + threadIdx.x;
  if (t < N_TOTAL*8) Q[t] = P[t] + b[t & 7];
}

__global__ void __launch_bounds__(256) k_scatter(const int* __restrict__ src,
                                                 const int* __restrict__ dst,
                                                 const float* __restrict__ P,
                                                 float* __restrict__ Q){
  int t = blockIdx.x*256 + threadIdx.x;
  int e = t >> 3;
  int j = t & 7;
  int s = src[e];
  int d = dst[e];
  float v = P[(size_t)s*8 + j];
  atomicAdd(Q + (size_t)d*8 + j, v);
}

// ---------------- readout ----------------
__global__ void __launch_bounds__(256) k_readout(const float* __restrict__ Q,
                          const float* __restrict__ wb, const float* __restrict__ bb,
                          const float* __restrict__ fc1w, const float* __restrict__ fc1b,
                          const float* __restrict__ fc2w, const float* __restrict__ fc2b,
                          float* __restrict__ out){
  int bi = blockIdx.x;
  int tid = threadIdx.x;
  float acc0 = 0.f, acc1 = 0.f;
  for (int n = tid; n < 2000; n += 256){
    size_t i = (size_t)bi*2000 + n;
    const float4* qr = (const float4*)(Q + i*8);
    float4 q0 = qr[0], q1 = qr[1];
    float g[8] = {lrelu(q0.x),lrelu(q0.y),lrelu(q0.z),lrelu(q0.w),
                  lrelu(q1.x),lrelu(q1.y),lrelu(q1.z),lrelu(q1.w)};
    float s = fc1b[0];
    #pragma unroll
    for (int j=0;j<8;j++){
      float h = bb[j];
      #pragma unroll
      for (int k=0;k<8;k++) h += g[k]*wb[k*8+j];
      s += lrelu(h)*fc1w[j];
    }
    float t = lrelu(s);
    acc0 += t*fc2w[n*2+0];
    acc1 += t*fc2w[n*2+1];
  }
  #pragma unroll
  for (int off = 32; off > 0; off >>= 1){
    acc0 += __shfl_down(acc0, off);
    acc1 += __shfl_down(acc1, off);
  }
  __shared__ float s0[4], s1[4];
  int w = tid >> 6;
  if ((tid & 63) == 0){ s0[w] = acc0; s1[w] = acc1; }
  __syncthreads();
  if (tid == 0){
    float z0 = s0[0]+s0[1]+s0[2]+s0[3] + fc2b[0];
    float z1 = s1[0]+s1[1]+s1[2]+s1[3] + fc2b[1];
    float m = fmaxf(z0, z1);
    float lse = m + logf(expf(z0-m) + expf(z1-m));
    out[bi*2+0] = z0 - lse;
    out[bi*2+1] = z1 - lse;
  }
}

extern "C" void kernel_launch(void* const* d_in, const int* in_sizes, int n_in,
                              void* d_out, int out_size, void* d_ws, size_t ws_size,
                              hipStream_t stream){
  const float* x   = (const float*)d_in[0];
  const int*   ei  = (const int*)d_in[1];
  const int*   src = ei;
  const int*   dst = ei + N_EDGES;
  const float* w0a=(const float*)d_in[3],  *b0a=(const float*)d_in[4];
  const float* w0b=(const float*)d_in[5],  *b0b=(const float*)d_in[6];
  const float* w1a=(const float*)d_in[7],  *b1a=(const float*)d_in[8];
  const float* w1b=(const float*)d_in[9],  *b1b=(const float*)d_in[10];
  const float* w2a=(const float*)d_in[11], *b2a=(const float*)d_in[12];
  const float* w2b=(const float*)d_in[13], *b2b=(const float*)d_in[14];
  const float* w3a=(const float*)d_in[15], *b3a=(const float*)d_in[16];
  const float* w3b=(const float*)d_in[17], *b3b=(const float*)d_in[18];
  const float* fc1w=(const float*)d_in[19],*fc1b=(const float*)d_in[20];
  const float* fc2w=(const float*)d_in[21],*fc2b=(const float*)d_in[22];
  float* out = (float*)d_out;

  // workspace layout
  char* base = (char*)d_ws;
  float* P       = (float*)base;                                  base += (size_t)N_TOTAL*8*4;   // 32.77 MB
  float* Q       = (float*)base;                                  base += (size_t)N_TOTAL*8*4;   // 32.77 MB
  size_t fallback_need = (size_t)(base - (char*)d_ws);
  int*   deg     = (int*)base;                                    base += (size_t)N_TOTAL*4;     // 4.10 MB (reused as pos)
  int*   row_ptr = (int*)base;                                    base += (size_t)(N_TOTAL+64)*4;// 4.10 MB
  int*   partial = (int*)base;                                    base += 4096;                  // 1000 block sums
  int*   csr     = (int*)base;                                    base += (size_t)N_EDGES*4;     // 65.54 MB
  size_t need = (size_t)(base - (char*)d_ws);

  const int nb_nodes = (N_TOTAL + 255)/256;     // 4000
  const int nb_edges = (N_EDGES + 255)/256;     // 64000
  const int nb_nf    = (N_TOTAL*8 + 255)/256;   // 32000

  if (ws_size >= need){
    // ---- CSR build (once per call, reused by all 4 layers) ----
    hipMemsetAsync(deg, 0, (size_t)N_TOTAL*4, stream);
    k_hist <<<nb_edges,256,0,stream>>>(dst, deg);
    k_scan1<<<1000,256,0,stream>>>(deg, partial);
    k_scan2<<<1,256,0,stream>>>(partial, 1000);
    k_scan3<<<1000,256,0,stream>>>(deg, partial, row_ptr, deg /*pos aliases deg*/);
    k_fill <<<nb_edges,256,0,stream>>>(src, dst, deg, csr);

    k_init<<<nb_nodes,256,0,stream>>>(x, w0a, P);
    k_agg <<<nb_nf,256,0,stream>>>(P, row_ptr, csr, b0a, Q);
    k_mid <<<nb_nodes,256,0,stream>>>(P, Q, w0b, b0b, w1a);
    k_agg <<<nb_nf,256,0,stream>>>(P, row_ptr, csr, b1a, Q);
    k_mid <<<nb_nodes,256,0,stream>>>(P, Q, w1b, b1b, w2a);
    k_agg <<<nb_nf,256,0,stream>>>(P, row_ptr, csr, b2a, Q);
    k_mid <<<nb_nodes,256,0,stream>>>(P, Q, w2b, b2b, w3a);
    k_agg <<<nb_nf,256,0,stream>>>(P, row_ptr, csr, b3a, Q);
  } else if (ws_size >= fallback_need){
    // ---- atomic fallback ----
    k_init<<<nb_nodes,256,0,stream>>>(x, w0a, P);
    k_qinit<<<nb_nf,256,0,stream>>>(P, b0a, Q);
    k_scatter<<<(N_EDGES*8)/256,256,0,stream>>>(src,dst,P,Q);
    k_mid <<<nb_nodes,256,0,stream>>>(P, Q, w0b, b0b, w1a);
    k_qinit<<<nb_nf,256,0,stream>>>(P, b1a, Q);
    k_scatter<<<(N_EDGES*8)/256,256,0,stream>>>(src,dst,P,Q);
    k_mid <<<nb_nodes,256,0,stream>>>(P, Q, w1b, b1b, w2a);
    k_qinit<<<nb_nf,256,0,stream>>>(P, b2a, Q);
    k_scatter<<<(N_EDGES*8)/256,256,0,stream>>>(src,dst,P,Q);
    k_mid <<<nb_nodes,256,0,stream>>>(P, Q, w2b, b2b, w3a);
    k_qinit<<<nb_nf,256,0,stream>>>(P, b3a, Q);
    k_scatter<<<(N_EDGES*8)/256,256,0,stream>>>(src,dst,P,Q);
  }
  k_readout<<<512,256,0,stream>>>(Q,w3b,b3b,fc1w,fc1b,fc2w,fc2b,out);
}

// Round 3
// 2548.466 us; speedup vs baseline: 1.3601x; 1.1736x over previous
//
#include <hip/hip_runtime.h>

#define N_TOTAL 1024000
#define N_EDGES 16384000
#define SLOPE 0.01f
#define NBUCK 4000     // buckets of 256 dst nodes each (4000*256 == N_TOTAL)
#define BCAP  5120     // mean 4096 edges/bucket, +16 sigma slack

__device__ __forceinline__ float lrelu(float v){ return v > 0.0f ? v : SLOPE*v; }

// ---------------- node kernels ----------------

// P[i] = x[i] @ w0a   (bias added later by aggregator)
__global__ void __launch_bounds__(256) k_init(const float* __restrict__ x,
                       const float* __restrict__ w,   // 16x8
                       float* __restrict__ P){
  int i = blockIdx.x*256 + threadIdx.x;
  if (i >= N_TOTAL) return;
  const float4* xr = (const float4*)(x + (size_t)i*16);
  float4 a0 = xr[0], a1 = xr[1], a2 = xr[2], a3 = xr[3];
  float xi[16] = {a0.x,a0.y,a0.z,a0.w, a1.x,a1.y,a1.z,a1.w,
                  a2.x,a2.y,a2.z,a2.w, a3.x,a3.y,a3.z,a3.w};
  float p[8];
  #pragma unroll
  for (int j=0;j<8;j++){
    float s = 0.f;
    #pragma unroll
    for (int k=0;k<16;k++) s += xi[k]*w[k*8+j];
    p[j] = s;
  }
  float4* Pr = (float4*)(P + (size_t)i*8);
  Pr[0] = make_float4(p[0],p[1],p[2],p[3]);
  Pr[1] = make_float4(p[4],p[5],p[6],p[7]);
}

// Q -> lrelu -> @wb+bb -> lrelu -> @wa -> P
__global__ void __launch_bounds__(256) k_mid(float* __restrict__ P, const float* __restrict__ Q,
                      const float* __restrict__ wb, const float* __restrict__ bb,
                      const float* __restrict__ wa){
  int i = blockIdx.x*256 + threadIdx.x;
  if (i >= N_TOTAL) return;
  const float4* Qr = (const float4*)(Q + (size_t)i*8);
  float4 q0 = Qr[0], q1 = Qr[1];
  float g[8] = {lrelu(q0.x),lrelu(q0.y),lrelu(q0.z),lrelu(q0.w),
                lrelu(q1.x),lrelu(q1.y),lrelu(q1.z),lrelu(q1.w)};
  float h[8];
  #pragma unroll
  for (int j=0;j<8;j++){
    float s = bb[j];
    #pragma unroll
    for (int k=0;k<8;k++) s += g[k]*wb[k*8+j];
    h[j] = lrelu(s);
  }
  float p[8];
  #pragma unroll
  for (int j=0;j<8;j++){
    float s = 0.f;
    #pragma unroll
    for (int k=0;k<8;k++) s += h[k]*wa[k*8+j];
    p[j] = s;
  }
  float4* Pr = (float4*)(P + (size_t)i*8);
  Pr[0] = make_float4(p[0],p[1],p[2],p[3]);
  Pr[1] = make_float4(p[4],p[5],p[6],p[7]);
}

// ---------------- binned CSR build (dense writes) ----------------

// Pass 1: bin edges by dst>>8; append packed (local<<20)|src into bucket region.
__global__ void __launch_bounds__(256) k_bin(const int* __restrict__ src, const int* __restrict__ dst,
                                             int* __restrict__ cnt, int* __restrict__ packed){
  int t = blockIdx.x*256 + threadIdx.x;
  if (t >= N_EDGES) return;
  int d = dst[t], s = src[t];
  int b = d >> 8, l = d & 255;
  int p = atomicAdd(&cnt[b], 1);
  if (p < BCAP) packed[b*BCAP + p] = (l << 20) | s;
}

// Pass 2: per bucket, LDS-stage edges, hist+scan over 256 local nodes,
// rewrite bucket region in place as per-node-sorted src lists; emit (beg,end).
__global__ void __launch_bounds__(256) k_csr(int* __restrict__ packed, const int* __restrict__ cnt,
                                             int2* __restrict__ row2){
  __shared__ int ebuf[BCAP];
  __shared__ int hist[256], pos[256], tmp[256];
  int b = blockIdx.x, tid = threadIdx.x;
  int n = cnt[b]; if (n > BCAP) n = BCAP;
  int* region = packed + (size_t)b*BCAP;
  hist[tid] = 0;
  __syncthreads();
  for (int i = tid; i < n; i += 256){
    int e = region[i];
    ebuf[i] = e;
    atomicAdd(&hist[e >> 20], 1);
  }
  __syncthreads();
  int v = hist[tid];
  tmp[tid] = v; __syncthreads();
  for (int off=1; off<256; off<<=1){
    int t2 = (tid>=off) ? tmp[tid-off] : 0; __syncthreads();
    tmp[tid] += t2; __syncthreads();
  }
  int ex = tmp[tid] - v;                 // exclusive scan
  pos[tid] = ex;
  int base = b*BCAP;
  row2[b*256 + tid] = make_int2(base + ex, base + ex + v);
  __syncthreads();
  for (int i = tid; i < n; i += 256){
    int e = ebuf[i];
    int l = e >> 20, s = e & 0xFFFFF;
    int p = atomicAdd(&pos[l], 1);
    region[p] = s;
  }
}

// ---------------- aggregation (no atomics) ----------------
// Q[i][j] = P[i][j] + b[j] + sum_{s in N(i)} P[s][j]; 8 lanes per node
__global__ void __launch_bounds__(256) k_agg(const float* __restrict__ P,
                                             const int2* __restrict__ row2,
                                             const int* __restrict__ csr,
                                             const float* __restrict__ b,
                                             float* __restrict__ Q){
  int t = blockIdx.x*256 + threadIdx.x;
  int node = t >> 3;
  int j = t & 7;
  if (node >= N_TOTAL) return;
  int2 r = row2[node];
  float acc = P[(size_t)node*8 + j] + b[j];
  int e = r.x;
  for (; e+3 < r.y; e += 4){
    int s0 = csr[e], s1 = csr[e+1], s2 = csr[e+2], s3 = csr[e+3];
    float v0 = P[(size_t)s0*8 + j];
    float v1 = P[(size_t)s1*8 + j];
    float v2 = P[(size_t)s2*8 + j];
    float v3 = P[(size_t)s3*8 + j];
    acc += v0; acc += v1; acc += v2; acc += v3;
  }
  for (; e < r.y; e++) acc += P[(size_t)csr[e]*8 + j];
  Q[(size_t)node*8 + j] = acc;
}

// ---------------- fallback (atomic path) ----------------
__global__ void __launch_bounds__(256) k_qinit(const float* __restrict__ P, const float* __restrict__ b,
                                               float* __restrict__ Q){
  int t = blockIdx.x*256 + threadIdx.x;
  if (t < N_TOTAL*8) Q[t] = P[t] + b[t & 7];
}

__global__ void __launch_bounds__(256) k_scatter(const int* __restrict__ src,
                                                 const int* __restrict__ dst,
                                                 const float* __restrict__ P,
                                                 float* __restrict__ Q){
  int t = blockIdx.x*256 + threadIdx.x;
  int e = t >> 3;
  int j = t & 7;
  int s = src[e];
  int d = dst[e];
  float v = P[(size_t)s*8 + j];
  atomicAdd(Q + (size_t)d*8 + j, v);
}

// ---------------- readout ----------------
__global__ void __launch_bounds__(256) k_readout(const float* __restrict__ Q,
                          const float* __restrict__ wb, const float* __restrict__ bb,
                          const float* __restrict__ fc1w, const float* __restrict__ fc1b,
                          const float* __restrict__ fc2w, const float* __restrict__ fc2b,
                          float* __restrict__ out){
  int bi = blockIdx.x;
  int tid = threadIdx.x;
  float acc0 = 0.f, acc1 = 0.f;
  for (int n = tid; n < 2000; n += 256){
    size_t i = (size_t)bi*2000 + n;
    const float4* qr = (const float4*)(Q + i*8);
    float4 q0 = qr[0], q1 = qr[1];
    float g[8] = {lrelu(q0.x),lrelu(q0.y),lrelu(q0.z),lrelu(q0.w),
                  lrelu(q1.x),lrelu(q1.y),lrelu(q1.z),lrelu(q1.w)};
    float s = fc1b[0];
    #pragma unroll
    for (int j=0;j<8;j++){
      float h = bb[j];
      #pragma unroll
      for (int k=0;k<8;k++) h += g[k]*wb[k*8+j];
      s += lrelu(h)*fc1w[j];
    }
    float t = lrelu(s);
    acc0 += t*fc2w[n*2+0];
    acc1 += t*fc2w[n*2+1];
  }
  #pragma unroll
  for (int off = 32; off > 0; off >>= 1){
    acc0 += __shfl_down(acc0, off);
    acc1 += __shfl_down(acc1, off);
  }
  __shared__ float s0[4], s1[4];
  int w = tid >> 6;
  if ((tid & 63) == 0){ s0[w] = acc0; s1[w] = acc1; }
  __syncthreads();
  if (tid == 0){
    float z0 = s0[0]+s0[1]+s0[2]+s0[3] + fc2b[0];
    float z1 = s1[0]+s1[1]+s1[2]+s1[3] + fc2b[1];
    float m = fmaxf(z0, z1);
    float lse = m + logf(expf(z0-m) + expf(z1-m));
    out[bi*2+0] = z0 - lse;
    out[bi*2+1] = z1 - lse;
  }
}

extern "C" void kernel_launch(void* const* d_in, const int* in_sizes, int n_in,
                              void* d_out, int out_size, void* d_ws, size_t ws_size,
                              hipStream_t stream){
  const float* x   = (const float*)d_in[0];
  const int*   ei  = (const int*)d_in[1];
  const int*   src = ei;
  const int*   dst = ei + N_EDGES;
  const float* w0a=(const float*)d_in[3],  *b0a=(const float*)d_in[4];
  const float* w0b=(const float*)d_in[5],  *b0b=(const float*)d_in[6];
  const float* w1a=(const float*)d_in[7],  *b1a=(const float*)d_in[8];
  const float* w1b=(const float*)d_in[9],  *b1b=(const float*)d_in[10];
  const float* w2a=(const float*)d_in[11], *b2a=(const float*)d_in[12];
  const float* w2b=(const float*)d_in[13], *b2b=(const float*)d_in[14];
  const float* w3a=(const float*)d_in[15], *b3a=(const float*)d_in[16];
  const float* w3b=(const float*)d_in[17], *b3b=(const float*)d_in[18];
  const float* fc1w=(const float*)d_in[19],*fc1b=(const float*)d_in[20];
  const float* fc2w=(const float*)d_in[21],*fc2b=(const float*)d_in[22];
  float* out = (float*)d_out;

  // workspace layout (new binned path)
  char* base = (char*)d_ws;
  float* P      = (float*)base;  base += (size_t)N_TOTAL*8*4;        // 32.77 MB
  float* Q      = (float*)base;  base += (size_t)N_TOTAL*8*4;        // 32.77 MB
  size_t atomic_need = (size_t)(base - (char*)d_ws);
  int2*  row2   = (int2*)base;   base += (size_t)N_TOTAL*8;          // 8.19 MB
  int*   cnt    = (int*)base;    base += 4096*4;                     // 16 KB
  int*   packed = (int*)base;    base += (size_t)NBUCK*BCAP*4;       // 81.92 MB
  size_t need = (size_t)(base - (char*)d_ws);

  const int nb_nodes = (N_TOTAL + 255)/256;     // 4000
  const int nb_edges = (N_EDGES + 255)/256;     // 64000
  const int nb_nf    = (N_TOTAL*8 + 255)/256;   // 32000

  if (ws_size >= need){
    // ---- binned CSR build (once per call, reused by all 4 layers) ----
    hipMemsetAsync(cnt, 0, (size_t)NBUCK*4, stream);
    k_bin<<<nb_edges,256,0,stream>>>(src, dst, cnt, packed);
    k_csr<<<NBUCK,256,0,stream>>>(packed, cnt, row2);

    k_init<<<nb_nodes,256,0,stream>>>(x, w0a, P);
    k_agg <<<nb_nf,256,0,stream>>>(P, row2, packed, b0a, Q);
    k_mid <<<nb_nodes,256,0,stream>>>(P, Q, w0b, b0b, w1a);
    k_agg <<<nb_nf,256,0,stream>>>(P, row2, packed, b1a, Q);
    k_mid <<<nb_nodes,256,0,stream>>>(P, Q, w1b, b1b, w2a);
    k_agg <<<nb_nf,256,0,stream>>>(P, row2, packed, b2a, Q);
    k_mid <<<nb_nodes,256,0,stream>>>(P, Q, w2b, b2b, w3a);
    k_agg <<<nb_nf,256,0,stream>>>(P, row2, packed, b3a, Q);
  } else if (ws_size >= atomic_need){
    // ---- atomic fallback ----
    k_init<<<nb_nodes,256,0,stream>>>(x, w0a, P);
    k_qinit<<<nb_nf,256,0,stream>>>(P, b0a, Q);
    k_scatter<<<(N_EDGES*8)/256,256,0,stream>>>(src,dst,P,Q);
    k_mid <<<nb_nodes,256,0,stream>>>(P, Q, w0b, b0b, w1a);
    k_qinit<<<nb_nf,256,0,stream>>>(P, b1a, Q);
    k_scatter<<<(N_EDGES*8)/256,256,0,stream>>>(src,dst,P,Q);
    k_mid <<<nb_nodes,256,0,stream>>>(P, Q, w1b, b1b, w2a);
    k_qinit<<<nb_nf,256,0,stream>>>(P, b2a, Q);
    k_scatter<<<(N_EDGES*8)/256,256,0,stream>>>(src,dst,P,Q);
    k_mid <<<nb_nodes,256,0,stream>>>(P, Q, w2b, b2b, w3a);
    k_qinit<<<nb_nf,256,0,stream>>>(P, b3a, Q);
    k_scatter<<<(N_EDGES*8)/256,256,0,stream>>>(src,dst,P,Q);
  }
  k_readout<<<512,256,0,stream>>>(Q,w3b,b3b,fc1w,fc1b,fc2w,fc2b,out);
}